// Round 5
// baseline (263.952 us; speedup 1.0000x reference)
//
#include <hip/hip_runtime.h>

// CausalSelfAttention B=4, N=2048, D=1024, scale 1/32.
// conv f32->f16 -> W transpose -> fused QKV GEMM (128x128, BK=64,
// global_load_lds) -> S=QK^T 128x128 (per-tile max-subtracted exp, writes
// P=exp(s-m_tile), per-tile m/l) -> combine (global m/l per row, factors F)
// -> PV 128x128 (stages P*F, causal K-limit, heavy-first, /l_g).
//
// R16: fixes R15's inf. Root cause: S's 16-lane butterfly reduced over one
// wave's 64 columns only, and BOTH wn-waves raced the M/L row stores
// (lr==0 true in all waves). Row 0: masked wave wrote m=-3e38,l=0 ->
// combine F=1, l_g=0 -> 1/0 = inf. Fix: cross-wave combine via 2KB LDS
// (sm_m/sm_s [wm][wn][64]): true per-row tile max before exp, summed l
// across wn-halves, single-writer (wn==0 wave) M/L stores. Still exact
// two-stage flash softmax, no atomics, deterministic, f16-safe at any
// input scale (P in (0,1]).

typedef __attribute__((ext_vector_type(8))) _Float16 half8;
typedef __attribute__((ext_vector_type(4))) _Float16 half4v;
typedef __attribute__((ext_vector_type(4))) float floatx4;

#define AS1 __attribute__((address_space(1)))
#define AS3 __attribute__((address_space(3)))

__device__ __forceinline__ void load16_lds(void* lds, const void* g) {
  __builtin_amdgcn_global_load_lds((AS1 void*)g, (AS3 void*)lds, 16, 0, 0);
}

// ---------------------------------------------------------------- conv

__global__ __launch_bounds__(256)
void conv_f32_f16(const float* __restrict__ in, _Float16* __restrict__ out) {
  const int i = (blockIdx.x * 256 + threadIdx.x) << 2;
  float4 v = *(const float4*)(in + i);
  half4v o = { (_Float16)v.x, (_Float16)v.y, (_Float16)v.z, (_Float16)v.w };
  *(half4v*)(out + i) = o;
}

// W [1024(k),1024(n)] fp32 -> Wt [n][k] f16 for 3 weights -> [3072][1024]
__global__ __launch_bounds__(256)
void transpose_w(const float* __restrict__ W0, const float* __restrict__ W1,
                 const float* __restrict__ W2, _Float16* __restrict__ Wt) {
  const float* W = blockIdx.z == 0 ? W0 : (blockIdx.z == 1 ? W1 : W2);
  _Float16* out = Wt + (long long)blockIdx.z * 1048576;
  __shared__ _Float16 t[32][33];
  const int tx = threadIdx.x, ty = threadIdx.y;
  const int n0 = blockIdx.x << 5, k0 = blockIdx.y << 5;
#pragma unroll
  for (int i = 0; i < 4; ++i)
    t[ty + i * 8][tx] = (_Float16)W[(long long)(k0 + ty + i * 8) * 1024 + n0 + tx];
  __syncthreads();
#pragma unroll
  for (int i = 0; i < 4; ++i)
    out[(long long)(n0 + ty + i * 8) * 1024 + k0 + tx] = t[tx][ty + i * 8];
}

// ---------------------------------------------------------------- QKV GEMM
// R11 kernel (736 TF, conflicts 0): 128x128 tile, BK=64, 4 waves 2x2.
__global__ __launch_bounds__(256)
void gemm_qkv(const _Float16* __restrict__ A, const _Float16* __restrict__ B,
              _Float16* __restrict__ Q, _Float16* __restrict__ Kh,
              _Float16* __restrict__ Vt) {
  const int bm = blockIdx.y, bn = blockIdx.x;
  const _Float16* Ab = A + (long long)bm * 128 * 1024;
  const _Float16* Bb = B + (long long)bn * 128 * 1024;

  __shared__ _Float16 As[128][64];
  __shared__ _Float16 Bs[128][64];

  const int tid = threadIdx.x;
  const int wave = tid >> 6, lane = tid & 63;
  const int quad = lane >> 4, lr = lane & 15;
  const int wm = (wave >> 1) << 6, wn = (wave & 1) << 6;
  const int srow = lane >> 3;
  const int goff = ((lane & 7) ^ srow) << 3;

  floatx4 acc[4][4] = {};
  const _Float16* ga = Ab + (long long)(wave * 8 + srow) * 1024 + goff;
  const _Float16* gb = Bb + (long long)(wave * 8 + srow) * 1024 + goff;

  for (int k0 = 0; k0 < 1024; k0 += 64) {
    __syncthreads();
#pragma unroll
    for (int c = 0; c < 4; ++c) {
      load16_lds(&As[wave * 8 + 32 * c][0], ga + c * 32 * 1024);
      load16_lds(&Bs[wave * 8 + 32 * c][0], gb + c * 32 * 1024);
    }
    ga += 64; gb += 64;
    __syncthreads();

#pragma unroll
    for (int kk = 0; kk < 2; ++kk) {
      half8 af[4], bf[4];
#pragma unroll
      for (int i = 0; i < 4; ++i) {
        const int ra = wm + (i << 4) + lr;
        const int rb = wn + (i << 4) + lr;
        af[i] = *(const half8*)&As[ra][(((kk << 2) + quad) ^ (ra & 7)) << 3];
        bf[i] = *(const half8*)&Bs[rb][(((kk << 2) + quad) ^ (rb & 7)) << 3];
      }
#pragma unroll
      for (int i = 0; i < 4; ++i)
#pragma unroll
        for (int j = 0; j < 4; ++j)
          acc[i][j] = __builtin_amdgcn_mfma_f32_16x16x32_f16(af[i], bf[j], acc[i][j], 0, 0, 0);
    }
  }

  const int colb = bn * 128 + wn + lr;
  const int rowb = bm * 128 + wm + (quad << 2);

  if (bn < 16) {
    _Float16* C = (bn < 8) ? Q : Kh;
    const int cb = colb & 1023;
#pragma unroll
    for (int i = 0; i < 4; ++i)
#pragma unroll
      for (int j = 0; j < 4; ++j)
#pragma unroll
        for (int r = 0; r < 4; ++r)
          C[(long long)(rowb + (i << 4) + r) * 1024 + cb + (j << 4)] =
              (_Float16)acc[i][j][r];
  } else {
    const int b = rowb >> 11;
    const int tb = rowb & 2047;
#pragma unroll
    for (int i = 0; i < 4; ++i) {
      const int tok = tb + (i << 4);
#pragma unroll
      for (int j = 0; j < 4; ++j) {
        const int d = (colb & 1023) + (j << 4);
        half4v v = { (_Float16)acc[i][j][0], (_Float16)acc[i][j][1],
                     (_Float16)acc[i][j][2], (_Float16)acc[i][j][3] };
        *(half4v*)&Vt[(long long)b * 2097152 + (long long)d * 2048 + tok] = v;
      }
    }
  }
}

// ---------------------------------------------------------------- S GEMM
// P[128 q x 128 k] = exp(mask(Q K^T/32) - m_tile) f16 in (0,1];
// per-tile row max M[bz][bn][row] and row sum L[bz][bn][row].
// Cross-wave (wn-half) combine via LDS; single-writer stores, no atomics.
// Compact triangular grid bn <= bm (136 tiles/batch).
__global__ __launch_bounds__(256)
void gemm_s_exp(const _Float16* __restrict__ Q, const _Float16* __restrict__ Kh,
                _Float16* __restrict__ P, float* __restrict__ M,
                float* __restrict__ L) {
  int t = blockIdx.x;
  int bm = 0;
  for (;;) { const int c = bm + 1; if (t < c) break; t -= c; ++bm; }
  const int bn = t;
  const int bz = blockIdx.y;

  const _Float16* Ab = Q  + (long long)bz * 2097152 + (long long)bm * 128 * 1024;
  const _Float16* Bb = Kh + (long long)bz * 2097152 + (long long)bn * 128 * 1024;

  __shared__ _Float16 As[128][64];
  __shared__ _Float16 Bs[128][64];
  __shared__ float sm_m[2][2][64];   // [wm-half][wn-half][local row]
  __shared__ float sm_s[2][2][64];

  const int tid = threadIdx.x;
  const int wave = tid >> 6, lane = tid & 63;
  const int quad = lane >> 4, lr = lane & 15;
  const int wm = (wave >> 1) << 6, wn = (wave & 1) << 6;
  const int wm1 = wave >> 1, wn1 = wave & 1;
  const int srow = lane >> 3;
  const int schunk = lane & 7;                 // LDS slot this lane fills
  const int goff = (schunk ^ srow) << 3;       // global chunk -> slot^(r&7)

  floatx4 acc[4][4] = {};
  const _Float16* ga = Ab + (long long)(wave * 8 + srow) * 1024 + goff;
  const _Float16* gb = Bb + (long long)(wave * 8 + srow) * 1024 + goff;

  half8 pa[4], pb[4];
#pragma unroll
  for (int c = 0; c < 4; ++c) {
    pa[c] = *(const half8*)(ga + c * 32 * 1024);
    pb[c] = *(const half8*)(gb + c * 32 * 1024);
  }

  for (int it = 0; it < 16; ++it) {
    __syncthreads();
#pragma unroll
    for (int c = 0; c < 4; ++c) {
      *(half8*)&As[wave * 8 + 32 * c + srow][schunk << 3] = pa[c];
      *(half8*)&Bs[wave * 8 + 32 * c + srow][schunk << 3] = pb[c];
    }
    __syncthreads();
    if (it + 1 < 16) {
      const int k1 = (it + 1) << 6;
#pragma unroll
      for (int c = 0; c < 4; ++c) {
        pa[c] = *(const half8*)(ga + c * 32 * 1024 + k1);
        pb[c] = *(const half8*)(gb + c * 32 * 1024 + k1);
      }
    }

#pragma unroll
    for (int kk = 0; kk < 2; ++kk) {
      half8 af[4], bf[4];
#pragma unroll
      for (int i = 0; i < 4; ++i) {
        const int ra = wm + (i << 4) + lr;
        const int rb = wn + (i << 4) + lr;
        af[i] = *(const half8*)&As[ra][(((kk << 2) + quad) ^ (ra & 7)) << 3];
        bf[i] = *(const half8*)&Bs[rb][(((kk << 2) + quad) ^ (rb & 7)) << 3];
      }
#pragma unroll
      for (int i = 0; i < 4; ++i)
#pragma unroll
        for (int j = 0; j < 4; ++j)
          acc[i][j] = __builtin_amdgcn_mfma_f32_16x16x32_f16(af[i], bf[j], acc[i][j], 0, 0, 0);
    }
  }

  // ---- epilogue ----
  // Per-wave masked 64-col max -> cross-wn-wave combine (LDS) -> true tile
  // max m_t -> P = exp(s/32 - m_t) -> per-wave sums -> cross-wave sum ->
  // single-writer M/L.
  const int colb = bn * 128 + wn + lr;
  const int rowb = bm * 128 + wm + (quad << 2);
  _Float16* Pb = P + (long long)bz * 4194304;
  const float scl = 0.03125f;

  float mx[4][4], rs[4][4];
#pragma unroll
  for (int i = 0; i < 4; ++i)
#pragma unroll
    for (int r = 0; r < 4; ++r) { mx[i][r] = -3.0e38f; rs[i][r] = 0.f; }

#pragma unroll
  for (int i = 0; i < 4; ++i)
#pragma unroll
    for (int j = 0; j < 4; ++j)
#pragma unroll
      for (int r = 0; r < 4; ++r) {
        const int qr = rowb + (i << 4) + r;
        const int kcol = colb + (j << 4);
        if (kcol <= qr) mx[i][r] = fmaxf(mx[i][r], acc[i][j][r] * scl);
      }
#pragma unroll
  for (int i = 0; i < 4; ++i)
#pragma unroll
    for (int r = 0; r < 4; ++r) {
#pragma unroll
      for (int off = 1; off < 16; off <<= 1)
        mx[i][r] = fmaxf(mx[i][r], __shfl_xor(mx[i][r], off));
    }

  // publish per-wave max, combine across wn-halves
  if (lr == 0) {
#pragma unroll
    for (int i = 0; i < 4; ++i)
#pragma unroll
      for (int r = 0; r < 4; ++r)
        sm_m[wm1][wn1][(i << 4) + (quad << 2) + r] = mx[i][r];
  }
  __syncthreads();
  float mt[4][4];
#pragma unroll
  for (int i = 0; i < 4; ++i)
#pragma unroll
    for (int r = 0; r < 4; ++r)
      mt[i][r] = fmaxf(mx[i][r], sm_m[wm1][wn1 ^ 1][(i << 4) + (quad << 2) + r]);

#pragma unroll
  for (int i = 0; i < 4; ++i)
#pragma unroll
    for (int j = 0; j < 4; ++j)
#pragma unroll
      for (int r = 0; r < 4; ++r) {
        const int qr = rowb + (i << 4) + r;
        const int kcol = colb + (j << 4);
        const float pv =
            (kcol <= qr) ? __expf(acc[i][j][r] * scl - mt[i][r]) : 0.f;
        Pb[(long long)qr * 2048 + kcol] = (_Float16)pv;
        rs[i][r] += pv;
      }

#pragma unroll
  for (int i = 0; i < 4; ++i)
#pragma unroll
    for (int r = 0; r < 4; ++r) {
#pragma unroll
      for (int off = 1; off < 16; off <<= 1)
        rs[i][r] += __shfl_xor(rs[i][r], off);
    }

  // publish per-wave sums, single writer (wn1==0 wave) stores M/L
  if (lr == 0) {
#pragma unroll
    for (int i = 0; i < 4; ++i)
#pragma unroll
      for (int r = 0; r < 4; ++r)
        sm_s[wm1][wn1][(i << 4) + (quad << 2) + r] = rs[i][r];
  }
  __syncthreads();
  if (wn1 == 0 && lr == 0) {
    float* Mb = M + ((long long)bz * 16 + bn) * 2048;
    float* Lb = L + ((long long)bz * 16 + bn) * 2048;
#pragma unroll
    for (int i = 0; i < 4; ++i)
#pragma unroll
      for (int r = 0; r < 4; ++r) {
        const int lrow = (i << 4) + (quad << 2) + r;
        const int row = rowb + (i << 4) + r;
        Mb[row] = mt[i][r];
        Lb[row] = rs[i][r] + sm_s[wm1][1][lrow];
      }
  }
}

// ---------------------------------------------------------------- combine
// Per row: m_g = max_t M[t], F[t] = exp(M[t]-m_g), l_g = sum F[t]*L[t].
// Only tiles t <= row>>7 are valid (triangular).
__global__ __launch_bounds__(256)
void combine(const float* __restrict__ M, const float* __restrict__ L,
             float* __restrict__ F, float* __restrict__ lg) {
  const int idx = blockIdx.x * 256 + threadIdx.x;  // 0..8191
  const int bz = idx >> 11, row = idx & 2047;
  const int nt = (row >> 7) + 1;
  const float* Mb = M + (long long)bz * 32768;
  const float* Lb = L + (long long)bz * 32768;
  float* Fb = F + (long long)bz * 32768;

  float mg = -3.0e38f;
  for (int t = 0; t < nt; ++t) mg = fmaxf(mg, Mb[t * 2048 + row]);
  float s = 0.f;
  for (int t = 0; t < nt; ++t) {
    const float f = __expf(Mb[t * 2048 + row] - mg);
    Fb[t * 2048 + row] = f;
    s += f * Lb[t * 2048 + row];
  }
  lg[bz * 2048 + row] = s;
}

// ---------------------------------------------------------------- PV GEMM
// out[128 q x 128 d] = (sum_kt F[kt]*P_kt V_kt) / l_g[q];
// Keff = 128*(bm+1); heavy-first. F folded into A-staging (packed f16 mul).
__global__ __launch_bounds__(256)
void gemm_pv(const _Float16* __restrict__ P, const _Float16* __restrict__ Vt,
             const float* __restrict__ F, const float* __restrict__ lg,
             float* __restrict__ out) {
  const int dn = blockIdx.x;           // 0..7
  const int bm = 15 - blockIdx.y;      // heavy (large Keff) first
  const int bz = blockIdx.z;
  const int niter = 2 * (bm + 1);      // Keff/64

  const _Float16* Ab = P  + (long long)bz * 4194304 + (long long)bm * 128 * 2048;
  const _Float16* Bb = Vt + (long long)bz * 2097152 + (long long)dn * 128 * 2048;
  const float* Fb = F + (long long)bz * 32768 + (long long)bm * 128;

  __shared__ _Float16 As[128][64];
  __shared__ _Float16 Bs[128][64];

  const int tid = threadIdx.x;
  const int wave = tid >> 6, lane = tid & 63;
  const int quad = lane >> 4, lr = lane & 15;
  const int wm = (wave >> 1) << 6, wn = (wave & 1) << 6;
  const int srow = lane >> 3;
  const int schunk = lane & 7;
  const int goff = (schunk ^ srow) << 3;
  const int lrow0 = wave * 8 + srow;   // tile-local staged row, chunk c: +32c

  floatx4 acc[4][4] = {};
  const _Float16* ga = Ab + (long long)lrow0 * 2048 + goff;
  const _Float16* gb = Bb + (long long)lrow0 * 2048 + goff;

  half8 pa[4], pb[4];
  float fr[4];
#pragma unroll
  for (int c = 0; c < 4; ++c) {
    pa[c] = *(const half8*)(ga + (long long)c * 32 * 2048);
    pb[c] = *(const half8*)(gb + (long long)c * 32 * 2048);
    fr[c] = Fb[lrow0 + 32 * c];        // kt = 0
  }

  for (int it = 0; it < niter; ++it) {
    __syncthreads();
#pragma unroll
    for (int c = 0; c < 4; ++c) {
      *(half8*)&As[wave * 8 + 32 * c + srow][schunk << 3] =
          pa[c] * (_Float16)fr[c];
      *(half8*)&Bs[wave * 8 + 32 * c + srow][schunk << 3] = pb[c];
    }
    __syncthreads();
    if (it + 1 < niter) {
      const int k1 = (it + 1) << 6;
      const int kt1 = (it + 1) >> 1;
#pragma unroll
      for (int c = 0; c < 4; ++c) {
        pa[c] = *(const half8*)(ga + (long long)c * 32 * 2048 + k1);
        pb[c] = *(const half8*)(gb + (long long)c * 32 * 2048 + k1);
        fr[c] = Fb[kt1 * 2048 + lrow0 + 32 * c];
      }
    }

#pragma unroll
    for (int kk = 0; kk < 2; ++kk) {
      half8 af[4], bf[4];
#pragma unroll
      for (int i = 0; i < 4; ++i) {
        const int ra = wm + (i << 4) + lr;
        const int rb = wn + (i << 4) + lr;
        af[i] = *(const half8*)&As[ra][(((kk << 2) + quad) ^ (ra & 7)) << 3];
        bf[i] = *(const half8*)&Bs[rb][(((kk << 2) + quad) ^ (rb & 7)) << 3];
      }
#pragma unroll
      for (int i = 0; i < 4; ++i)
#pragma unroll
        for (int j = 0; j < 4; ++j)
          acc[i][j] = __builtin_amdgcn_mfma_f32_16x16x32_f16(af[i], bf[j], acc[i][j], 0, 0, 0);
    }
  }

  const int colb = dn * 128 + wn + lr;
  const int rowb = bm * 128 + wm + (quad << 2);
  const float* lb = lg + bz * 2048;
  float* Cb = out + (long long)bz * 2097152;

  float linv[4][4];
#pragma unroll
  for (int i = 0; i < 4; ++i)
#pragma unroll
    for (int r = 0; r < 4; ++r)
      linv[i][r] = 1.0f / lb[rowb + (i << 4) + r];

#pragma unroll
  for (int i = 0; i < 4; ++i)
#pragma unroll
    for (int j = 0; j < 4; ++j)
#pragma unroll
      for (int r = 0; r < 4; ++r)
        Cb[(long long)(rowb + (i << 4) + r) * 1024 + colb + (j << 4)] =
            acc[i][j][r] * linv[i][r];
}

// ---------------------------------------------------------------- launch

extern "C" void kernel_launch(void* const* d_in, const int* in_sizes, int n_in,
                              void* d_out, int out_size, void* d_ws, size_t ws_size,
                              hipStream_t stream) {
  const float* x  = (const float*)d_in[0];
  const float* Wq = (const float*)d_in[1];
  const float* Wk = (const float*)d_in[2];
  const float* Wv = (const float*)d_in[3];
  float* out = (float*)d_out;

  char* ws = (char*)d_ws;
  _Float16* xh = (_Float16*)(ws);               // 8192x1024 f16   (16 MiB)
  _Float16* Wt = (_Float16*)(ws + 16777216);    // 3072x1024 f16   ( 6 MiB)
  _Float16* Q  = (_Float16*)(ws + 23068672);    // 8192x1024 f16
  _Float16* Kh = (_Float16*)(ws + 39845888);    // 8192x1024 f16
  _Float16* Vt = (_Float16*)(ws + 56623104);    // 4x1024x2048 f16
  _Float16* P  = (_Float16*)(ws + 73400320);    // 4x2048x2048 f16 (exp-m_tile)
  float*    M  = (float*)   (ws + 106954752);   // [4][16][2048] tile row max
  float*    L  = (float*)   (ws + 107479040);   // [4][16][2048] tile row sum
  float*    F  = (float*)   (ws + 108003328);   // [4][16][2048] rescale
  float*    lg = (float*)   (ws + 108527616);   // [4][2048] global row sum

  conv_f32_f16<<<8192, 256, 0, stream>>>(x, xh);
  transpose_w<<<dim3(32, 32, 3), dim3(32, 8), 0, stream>>>(Wq, Wk, Wv, Wt);

  // fused QKV: [8192,1024] x [3072,1024]^T
  gemm_qkv<<<dim3(24, 64), 256, 0, stream>>>(xh, Wt, Q, Kh, Vt);

  // P = exp(mask(Q K^T / 32) - m_tile), per-tile m/l; triangular grid
  gemm_s_exp<<<dim3(136, 4), 256, 0, stream>>>(Q, Kh, P, M, L);

  // per-row global max/sum + rescale factors
  combine<<<32, 256, 0, stream>>>(M, L, F, lg);

  // out = (sum F*P V) / l_g; causal K-limit at 128 gran, heavy-first
  gemm_pv<<<dim3(8, 16, 4), 256, 0, stream>>>(P, Vt, F, lg, out);
}

// Round 6
// 254.691 us; speedup vs baseline: 1.0364x; 1.0364x over previous
//
#include <hip/hip_runtime.h>

// CausalSelfAttention B=4, N=2048, D=1024, scale 1/32.
// prep (f32->f16 conv + W transpose) -> fused QKV GEMM (128x128, BK=64,
// global_load_lds) -> S=QK^T 128x128 (per-tile max-subtracted exp, P + M/L)
// -> combine (global m/l, factors F) -> PV 128x128 (stages P*F, /l_g).
//
// R17: PV XCD-grouping swizzle. Arithmetic: PV grid x-major => lid%8 == dn
// => every XCD streams ALL of P (33.5MB) through its L2 = 268MB HBM refetch
// (~42us) - why an 18.25 GFLOP GEMM took ~65-70us. Remap: xcd=lid&7 owns
// bm in {xcd, 15-xcd} (Keff sums 17 -> balanced) for all bz; all 8 dn of a
// (bm,bz) panel on one XCD -> P fetched once. Also re-applied R14's
// harness-timed-safe bundle: prep merge (zero-l dropped; flash path needs
// none), QKV swizzle (8 bm-rows/XCD), S swizzle (17 tri-ids/XCD).
// Numerics identical to R16 (exact two-stage flash softmax, no atomics).

typedef __attribute__((ext_vector_type(8))) _Float16 half8;
typedef __attribute__((ext_vector_type(4))) _Float16 half4v;
typedef __attribute__((ext_vector_type(4))) float floatx4;

#define AS1 __attribute__((address_space(1)))
#define AS3 __attribute__((address_space(3)))

__device__ __forceinline__ void load16_lds(void* lds, const void* g) {
  __builtin_amdgcn_global_load_lds((AS1 void*)g, (AS3 void*)lds, 16, 0, 0);
}

// ------------------------------------------------------------- merged prep
// blocks [0,8192): x f32->f16; [8192,11264): W transpose (32x32 tiles).
__global__ __launch_bounds__(256)
void prep(const float* __restrict__ in, _Float16* __restrict__ out,
          const float* __restrict__ W0, const float* __restrict__ W1,
          const float* __restrict__ W2, _Float16* __restrict__ Wt) {
  const int bid = blockIdx.x;
  if (bid < 8192) {
    const int i = (bid * 256 + threadIdx.x) << 2;
    float4 v = *(const float4*)(in + i);
    half4v o = { (_Float16)v.x, (_Float16)v.y, (_Float16)v.z, (_Float16)v.w };
    *(half4v*)(out + i) = o;
  } else {
    const int t = bid - 8192;              // 0..3071
    const int bz = t >> 10;                // 0..2
    const int rem = t & 1023;
    const int bx = rem & 31, by = rem >> 5;
    const float* W = bz == 0 ? W0 : (bz == 1 ? W1 : W2);
    _Float16* o = Wt + (long long)bz * 1048576;
    __shared__ _Float16 tl[32][33];
    const int tx = threadIdx.x & 31, ty = threadIdx.x >> 5;  // 32x8
    const int n0 = bx << 5, k0 = by << 5;
#pragma unroll
    for (int i = 0; i < 4; ++i)
      tl[ty + i * 8][tx] = (_Float16)W[(long long)(k0 + ty + i * 8) * 1024 + n0 + tx];
    __syncthreads();
#pragma unroll
    for (int i = 0; i < 4; ++i)
      o[(long long)(n0 + ty + i * 8) * 1024 + k0 + tx] = tl[tx][ty + i * 8];
  }
}

// ---------------------------------------------------------------- QKV GEMM
// R11 kernel (736 TF, conflicts 0): 128x128 tile, BK=64, 4 waves 2x2.
// XCD swizzle: each XCD gets 192 consecutive ids = 8 whole bm-rows.
__global__ __launch_bounds__(256)
void gemm_qkv(const _Float16* __restrict__ A, const _Float16* __restrict__ B,
              _Float16* __restrict__ Q, _Float16* __restrict__ Kh,
              _Float16* __restrict__ Vt) {
  const int lid = blockIdx.x + 24 * blockIdx.y;
  const int swz = (lid & 7) * 192 + (lid >> 3);
  const int bm = swz / 24, bn = swz % 24;

  const _Float16* Ab = A + (long long)bm * 128 * 1024;
  const _Float16* Bb = B + (long long)bn * 128 * 1024;

  __shared__ _Float16 As[128][64];
  __shared__ _Float16 Bs[128][64];

  const int tid = threadIdx.x;
  const int wave = tid >> 6, lane = tid & 63;
  const int quad = lane >> 4, lr = lane & 15;
  const int wm = (wave >> 1) << 6, wn = (wave & 1) << 6;
  const int srow = lane >> 3;
  const int goff = ((lane & 7) ^ srow) << 3;

  floatx4 acc[4][4] = {};
  const _Float16* ga = Ab + (long long)(wave * 8 + srow) * 1024 + goff;
  const _Float16* gb = Bb + (long long)(wave * 8 + srow) * 1024 + goff;

  for (int k0 = 0; k0 < 1024; k0 += 64) {
    __syncthreads();
#pragma unroll
    for (int c = 0; c < 4; ++c) {
      load16_lds(&As[wave * 8 + 32 * c][0], ga + c * 32 * 1024);
      load16_lds(&Bs[wave * 8 + 32 * c][0], gb + c * 32 * 1024);
    }
    ga += 64; gb += 64;
    __syncthreads();

#pragma unroll
    for (int kk = 0; kk < 2; ++kk) {
      half8 af[4], bf[4];
#pragma unroll
      for (int i = 0; i < 4; ++i) {
        const int ra = wm + (i << 4) + lr;
        const int rb = wn + (i << 4) + lr;
        af[i] = *(const half8*)&As[ra][(((kk << 2) + quad) ^ (ra & 7)) << 3];
        bf[i] = *(const half8*)&Bs[rb][(((kk << 2) + quad) ^ (rb & 7)) << 3];
      }
#pragma unroll
      for (int i = 0; i < 4; ++i)
#pragma unroll
        for (int j = 0; j < 4; ++j)
          acc[i][j] = __builtin_amdgcn_mfma_f32_16x16x32_f16(af[i], bf[j], acc[i][j], 0, 0, 0);
    }
  }

  const int colb = bn * 128 + wn + lr;
  const int rowb = bm * 128 + wm + (quad << 2);

  if (bn < 16) {
    _Float16* C = (bn < 8) ? Q : Kh;
    const int cb = colb & 1023;
#pragma unroll
    for (int i = 0; i < 4; ++i)
#pragma unroll
      for (int j = 0; j < 4; ++j)
#pragma unroll
        for (int r = 0; r < 4; ++r)
          C[(long long)(rowb + (i << 4) + r) * 1024 + cb + (j << 4)] =
              (_Float16)acc[i][j][r];
  } else {
    const int b = rowb >> 11;
    const int tb = rowb & 2047;
#pragma unroll
    for (int i = 0; i < 4; ++i) {
      const int tok = tb + (i << 4);
#pragma unroll
      for (int j = 0; j < 4; ++j) {
        const int d = (colb & 1023) + (j << 4);
        half4v v = { (_Float16)acc[i][j][0], (_Float16)acc[i][j][1],
                     (_Float16)acc[i][j][2], (_Float16)acc[i][j][3] };
        *(half4v*)&Vt[(long long)b * 2097152 + (long long)d * 2048 + tok] = v;
      }
    }
  }
}

// ---------------------------------------------------------------- S GEMM
// P[128 q x 128 k] = exp(mask(Q K^T/32) - m_tile) f16 in (0,1];
// per-tile row max M and row sum L, cross-wave combined via LDS.
// Triangular grid bn <= bm (136/batch) + XCD swizzle (8x17).
__global__ __launch_bounds__(256)
void gemm_s_exp(const _Float16* __restrict__ Q, const _Float16* __restrict__ Kh,
                _Float16* __restrict__ P, float* __restrict__ M,
                float* __restrict__ L) {
  // 136 = 8*17: 17 consecutive triangular ids per XCD -> same-bm blocks
  // (sharing the Q panel) co-reside in one XCD's L2.
  int t = (blockIdx.x & 7) * 17 + (blockIdx.x >> 3);
  int bm = 0;
  for (;;) { const int c = bm + 1; if (t < c) break; t -= c; ++bm; }
  const int bn = t;
  const int bz = blockIdx.y;

  const _Float16* Ab = Q  + (long long)bz * 2097152 + (long long)bm * 128 * 1024;
  const _Float16* Bb = Kh + (long long)bz * 2097152 + (long long)bn * 128 * 1024;

  __shared__ _Float16 As[128][64];
  __shared__ _Float16 Bs[128][64];
  __shared__ float sm_m[2][2][64];   // [wm-half][wn-half][local row]
  __shared__ float sm_s[2][2][64];

  const int tid = threadIdx.x;
  const int wave = tid >> 6, lane = tid & 63;
  const int quad = lane >> 4, lr = lane & 15;
  const int wm = (wave >> 1) << 6, wn = (wave & 1) << 6;
  const int wm1 = wave >> 1, wn1 = wave & 1;
  const int srow = lane >> 3;
  const int schunk = lane & 7;                 // LDS slot this lane fills
  const int goff = (schunk ^ srow) << 3;       // global chunk -> slot^(r&7)

  floatx4 acc[4][4] = {};
  const _Float16* ga = Ab + (long long)(wave * 8 + srow) * 1024 + goff;
  const _Float16* gb = Bb + (long long)(wave * 8 + srow) * 1024 + goff;

  half8 pa[4], pb[4];
#pragma unroll
  for (int c = 0; c < 4; ++c) {
    pa[c] = *(const half8*)(ga + c * 32 * 1024);
    pb[c] = *(const half8*)(gb + c * 32 * 1024);
  }

  for (int it = 0; it < 16; ++it) {
    __syncthreads();
#pragma unroll
    for (int c = 0; c < 4; ++c) {
      *(half8*)&As[wave * 8 + 32 * c + srow][schunk << 3] = pa[c];
      *(half8*)&Bs[wave * 8 + 32 * c + srow][schunk << 3] = pb[c];
    }
    __syncthreads();
    if (it + 1 < 16) {
      const int k1 = (it + 1) << 6;
#pragma unroll
      for (int c = 0; c < 4; ++c) {
        pa[c] = *(const half8*)(ga + c * 32 * 1024 + k1);
        pb[c] = *(const half8*)(gb + c * 32 * 1024 + k1);
      }
    }

#pragma unroll
    for (int kk = 0; kk < 2; ++kk) {
      half8 af[4], bf[4];
#pragma unroll
      for (int i = 0; i < 4; ++i) {
        const int ra = wm + (i << 4) + lr;
        const int rb = wn + (i << 4) + lr;
        af[i] = *(const half8*)&As[ra][(((kk << 2) + quad) ^ (ra & 7)) << 3];
        bf[i] = *(const half8*)&Bs[rb][(((kk << 2) + quad) ^ (rb & 7)) << 3];
      }
#pragma unroll
      for (int i = 0; i < 4; ++i)
#pragma unroll
        for (int j = 0; j < 4; ++j)
          acc[i][j] = __builtin_amdgcn_mfma_f32_16x16x32_f16(af[i], bf[j], acc[i][j], 0, 0, 0);
    }
  }

  // ---- epilogue: per-wave masked max -> cross-wn combine -> exp -> sums ->
  // single-writer M/L (wn1==0 wave).
  const int colb = bn * 128 + wn + lr;
  const int rowb = bm * 128 + wm + (quad << 2);
  _Float16* Pb = P + (long long)bz * 4194304;
  const float scl = 0.03125f;

  float mx[4][4], rs[4][4];
#pragma unroll
  for (int i = 0; i < 4; ++i)
#pragma unroll
    for (int r = 0; r < 4; ++r) { mx[i][r] = -3.0e38f; rs[i][r] = 0.f; }

#pragma unroll
  for (int i = 0; i < 4; ++i)
#pragma unroll
    for (int j = 0; j < 4; ++j)
#pragma unroll
      for (int r = 0; r < 4; ++r) {
        const int qr = rowb + (i << 4) + r;
        const int kcol = colb + (j << 4);
        if (kcol <= qr) mx[i][r] = fmaxf(mx[i][r], acc[i][j][r] * scl);
      }
#pragma unroll
  for (int i = 0; i < 4; ++i)
#pragma unroll
    for (int r = 0; r < 4; ++r) {
#pragma unroll
      for (int off = 1; off < 16; off <<= 1)
        mx[i][r] = fmaxf(mx[i][r], __shfl_xor(mx[i][r], off));
    }

  if (lr == 0) {
#pragma unroll
    for (int i = 0; i < 4; ++i)
#pragma unroll
      for (int r = 0; r < 4; ++r)
        sm_m[wm1][wn1][(i << 4) + (quad << 2) + r] = mx[i][r];
  }
  __syncthreads();
  float mt[4][4];
#pragma unroll
  for (int i = 0; i < 4; ++i)
#pragma unroll
    for (int r = 0; r < 4; ++r)
      mt[i][r] = fmaxf(mx[i][r], sm_m[wm1][wn1 ^ 1][(i << 4) + (quad << 2) + r]);

#pragma unroll
  for (int i = 0; i < 4; ++i)
#pragma unroll
    for (int j = 0; j < 4; ++j)
#pragma unroll
      for (int r = 0; r < 4; ++r) {
        const int qr = rowb + (i << 4) + r;
        const int kcol = colb + (j << 4);
        const float pv =
            (kcol <= qr) ? __expf(acc[i][j][r] * scl - mt[i][r]) : 0.f;
        Pb[(long long)qr * 2048 + kcol] = (_Float16)pv;
        rs[i][r] += pv;
      }

#pragma unroll
  for (int i = 0; i < 4; ++i)
#pragma unroll
    for (int r = 0; r < 4; ++r) {
#pragma unroll
      for (int off = 1; off < 16; off <<= 1)
        rs[i][r] += __shfl_xor(rs[i][r], off);
    }

  if (lr == 0) {
#pragma unroll
    for (int i = 0; i < 4; ++i)
#pragma unroll
      for (int r = 0; r < 4; ++r)
        sm_s[wm1][wn1][(i << 4) + (quad << 2) + r] = rs[i][r];
  }
  __syncthreads();
  if (wn1 == 0 && lr == 0) {
    float* Mb = M + ((long long)bz * 16 + bn) * 2048;
    float* Lb = L + ((long long)bz * 16 + bn) * 2048;
#pragma unroll
    for (int i = 0; i < 4; ++i)
#pragma unroll
      for (int r = 0; r < 4; ++r) {
        const int lrow = (i << 4) + (quad << 2) + r;
        const int row = rowb + (i << 4) + r;
        Mb[row] = mt[i][r];
        Lb[row] = rs[i][r] + sm_s[wm1][1][lrow];
      }
  }
}

// ---------------------------------------------------------------- combine
// Per row: m_g = max_t M[t], F[t] = exp(M[t]-m_g), l_g = sum F[t]*L[t].
__global__ __launch_bounds__(256)
void combine(const float* __restrict__ M, const float* __restrict__ L,
             float* __restrict__ F, float* __restrict__ lg) {
  const int idx = blockIdx.x * 256 + threadIdx.x;  // 0..8191
  const int bz = idx >> 11, row = idx & 2047;
  const int nt = (row >> 7) + 1;
  const float* Mb = M + (long long)bz * 32768;
  const float* Lb = L + (long long)bz * 32768;
  float* Fb = F + (long long)bz * 32768;

  float mg = -3.0e38f;
  for (int t = 0; t < nt; ++t) mg = fmaxf(mg, Mb[t * 2048 + row]);
  float s = 0.f;
  for (int t = 0; t < nt; ++t) {
    const float f = __expf(Mb[t * 2048 + row] - mg);
    Fb[t * 2048 + row] = f;
    s += f * Lb[t * 2048 + row];
  }
  lg[bz * 2048 + row] = s;
}

// ---------------------------------------------------------------- PV GEMM
// out[128 q x 128 d] = (sum_kt F[kt]*P_kt V_kt) / l_g[q]; Keff=128*(bm+1).
// XCD-grouping swizzle: xcd = lid&7 owns bm in {xcd, 15-xcd} (Keff sum 17,
// balanced) for all bz; all 8 dn of a (bm,bz) on one XCD -> P panel fetched
// once per XCD instead of 8x (268MB -> ~34MB HBM).
__global__ __launch_bounds__(256)
void gemm_pv(const _Float16* __restrict__ P, const _Float16* __restrict__ Vt,
             const float* __restrict__ F, const float* __restrict__ lg,
             float* __restrict__ out) {
  const int lid = blockIdx.x + (blockIdx.y << 3) + (blockIdx.z << 7);
  const int xcd = lid & 7, slot = lid >> 3;
  const int dn = slot & 7;             // 0..7
  const int p = slot >> 3;             // 0..7
  const int bz = p & 3;
  const int bm = (p >> 2) ? xcd : (15 - xcd);  // heavy half first
  const int niter = 2 * (bm + 1);      // Keff/64

  const _Float16* Ab = P  + (long long)bz * 4194304 + (long long)bm * 128 * 2048;
  const _Float16* Bb = Vt + (long long)bz * 2097152 + (long long)dn * 128 * 2048;
  const float* Fb = F + (long long)bz * 32768 + (long long)bm * 128;

  __shared__ _Float16 As[128][64];
  __shared__ _Float16 Bs[128][64];

  const int tid = threadIdx.x;
  const int wave = tid >> 6, lane = tid & 63;
  const int quad = lane >> 4, lr = lane & 15;
  const int wm = (wave >> 1) << 6, wn = (wave & 1) << 6;
  const int srow = lane >> 3;
  const int schunk = lane & 7;
  const int goff = (schunk ^ srow) << 3;
  const int lrow0 = wave * 8 + srow;   // tile-local staged row, chunk c: +32c

  floatx4 acc[4][4] = {};
  const _Float16* ga = Ab + (long long)lrow0 * 2048 + goff;
  const _Float16* gb = Bb + (long long)lrow0 * 2048 + goff;

  half8 pa[4], pb[4];
  float fr[4];
#pragma unroll
  for (int c = 0; c < 4; ++c) {
    pa[c] = *(const half8*)(ga + (long long)c * 32 * 2048);
    pb[c] = *(const half8*)(gb + (long long)c * 32 * 2048);
    fr[c] = Fb[lrow0 + 32 * c];        // kt = 0
  }

  for (int it = 0; it < niter; ++it) {
    __syncthreads();
#pragma unroll
    for (int c = 0; c < 4; ++c) {
      *(half8*)&As[wave * 8 + 32 * c + srow][schunk << 3] =
          pa[c] * (_Float16)fr[c];
      *(half8*)&Bs[wave * 8 + 32 * c + srow][schunk << 3] = pb[c];
    }
    __syncthreads();
    if (it + 1 < niter) {
      const int k1 = (it + 1) << 6;
      const int kt1 = (it + 1) >> 1;
#pragma unroll
      for (int c = 0; c < 4; ++c) {
        pa[c] = *(const half8*)(ga + (long long)c * 32 * 2048 + k1);
        pb[c] = *(const half8*)(gb + (long long)c * 32 * 2048 + k1);
        fr[c] = Fb[kt1 * 2048 + lrow0 + 32 * c];
      }
    }

#pragma unroll
    for (int kk = 0; kk < 2; ++kk) {
      half8 af[4], bf[4];
#pragma unroll
      for (int i = 0; i < 4; ++i) {
        const int ra = wm + (i << 4) + lr;
        const int rb = wn + (i << 4) + lr;
        af[i] = *(const half8*)&As[ra][(((kk << 2) + quad) ^ (ra & 7)) << 3];
        bf[i] = *(const half8*)&Bs[rb][(((kk << 2) + quad) ^ (rb & 7)) << 3];
      }
#pragma unroll
      for (int i = 0; i < 4; ++i)
#pragma unroll
        for (int j = 0; j < 4; ++j)
          acc[i][j] = __builtin_amdgcn_mfma_f32_16x16x32_f16(af[i], bf[j], acc[i][j], 0, 0, 0);
    }
  }

  const int colb = dn * 128 + wn + lr;
  const int rowb = bm * 128 + wm + (quad << 2);
  const float* lb = lg + bz * 2048;
  float* Cb = out + (long long)bz * 2097152;

  float linv[4][4];
#pragma unroll
  for (int i = 0; i < 4; ++i)
#pragma unroll
    for (int r = 0; r < 4; ++r)
      linv[i][r] = 1.0f / lb[rowb + (i << 4) + r];

#pragma unroll
  for (int i = 0; i < 4; ++i)
#pragma unroll
    for (int j = 0; j < 4; ++j)
#pragma unroll
      for (int r = 0; r < 4; ++r)
        Cb[(long long)(rowb + (i << 4) + r) * 1024 + colb + (j << 4)] =
            acc[i][j][r] * linv[i][r];
}

// ---------------------------------------------------------------- launch

extern "C" void kernel_launch(void* const* d_in, const int* in_sizes, int n_in,
                              void* d_out, int out_size, void* d_ws, size_t ws_size,
                              hipStream_t stream) {
  const float* x  = (const float*)d_in[0];
  const float* Wq = (const float*)d_in[1];
  const float* Wk = (const float*)d_in[2];
  const float* Wv = (const float*)d_in[3];
  float* out = (float*)d_out;

  char* ws = (char*)d_ws;
  _Float16* xh = (_Float16*)(ws);               // 8192x1024 f16   (16 MiB)
  _Float16* Wt = (_Float16*)(ws + 16777216);    // 3072x1024 f16   ( 6 MiB)
  _Float16* Q  = (_Float16*)(ws + 23068672);    // 8192x1024 f16
  _Float16* Kh = (_Float16*)(ws + 39845888);    // 8192x1024 f16
  _Float16* Vt = (_Float16*)(ws + 56623104);    // 4x1024x2048 f16
  _Float16* P  = (_Float16*)(ws + 73400320);    // 4x2048x2048 f16 (exp-m_tile)
  float*    M  = (float*)   (ws + 106954752);   // [4][16][2048] tile row max
  float*    L  = (float*)   (ws + 107479040);   // [4][16][2048] tile row sum
  float*    F  = (float*)   (ws + 108003328);   // [4][16][2048] rescale
  float*    lg = (float*)   (ws + 108527616);   // [4][2048] global row sum

  // merged: x convert + W transpose
  prep<<<11264, 256, 0, stream>>>(x, xh, Wq, Wk, Wv, Wt);

  // fused QKV: [8192,1024] x [3072,1024]^T
  gemm_qkv<<<dim3(24, 64), 256, 0, stream>>>(xh, Wt, Q, Kh, Vt);

  // P = exp(mask(Q K^T / 32) - m_tile), per-tile m/l; triangular grid
  gemm_s_exp<<<dim3(136, 4), 256, 0, stream>>>(Q, Kh, P, M, L);

  // per-row global max/sum + rescale factors
  combine<<<32, 256, 0, stream>>>(M, L, F, lg);

  // out = (sum F*P V) / l_g; XCD-grouped, balanced, heavy-first
  gemm_pv<<<dim3(8, 16, 4), 256, 0, stream>>>(P, Vt, F, lg, out);
}

// Round 7
// 241.356 us; speedup vs baseline: 1.0936x; 1.0552x over previous
//
#include <hip/hip_runtime.h>

// CausalSelfAttention B=4, N=2048, D=1024, scale 1/32.
// prep (f32->f16 conv + W transpose) -> fused QKV GEMM (128x128, BK=64,
// global_load_lds) -> S=QK^T 128x128 (per-tile max-subtracted exp, P + M/L)
// -> PV 128x128 swapped (C[d][q] = Vt . P^T, combine folded into prologue).
//
// R18: (a) PV operand swap: A=Vt[d][tok], B=P[q][k] (both already row-major
// in memory) -> C-fragment regs span 4 consecutive d -> float4 out stores
// (was scalar f32 @ stride 1024). (b) combine folded into PV prologue:
// per-block recompute of m_g/F/1/l for its 128 q-rows from M/L into LDS
// (8.5KB); removes combine kernel + launch gap + F/lg buffers + F global
// loads in staging. (c) PV XCD map 4 bm-groups x 2 dn-halves (bm groups
// {15,14,1,0}... each sum(bm+1)=34, heavy pair first): P read by 2 XCDs,
// Vt by 4 -> modeled fetch 160->70MB. (d) QKV swizzle reverted (R17 showed
// FETCH 77->84MB, dur unchanged). Numerics identical to R16/R17.

typedef __attribute__((ext_vector_type(8))) _Float16 half8;
typedef __attribute__((ext_vector_type(4))) _Float16 half4v;
typedef __attribute__((ext_vector_type(4))) float floatx4;

#define AS1 __attribute__((address_space(1)))
#define AS3 __attribute__((address_space(3)))

__device__ __forceinline__ void load16_lds(void* lds, const void* g) {
  __builtin_amdgcn_global_load_lds((AS1 void*)g, (AS3 void*)lds, 16, 0, 0);
}

// ------------------------------------------------------------- merged prep
// blocks [0,8192): x f32->f16; [8192,11264): W transpose (32x32 tiles).
__global__ __launch_bounds__(256)
void prep(const float* __restrict__ in, _Float16* __restrict__ out,
          const float* __restrict__ W0, const float* __restrict__ W1,
          const float* __restrict__ W2, _Float16* __restrict__ Wt) {
  const int bid = blockIdx.x;
  if (bid < 8192) {
    const int i = (bid * 256 + threadIdx.x) << 2;
    float4 v = *(const float4*)(in + i);
    half4v o = { (_Float16)v.x, (_Float16)v.y, (_Float16)v.z, (_Float16)v.w };
    *(half4v*)(out + i) = o;
  } else {
    const int t = bid - 8192;              // 0..3071
    const int bz = t >> 10;                // 0..2
    const int rem = t & 1023;
    const int bx = rem & 31, by = rem >> 5;
    const float* W = bz == 0 ? W0 : (bz == 1 ? W1 : W2);
    _Float16* o = Wt + (long long)bz * 1048576;
    __shared__ _Float16 tl[32][33];
    const int tx = threadIdx.x & 31, ty = threadIdx.x >> 5;  // 32x8
    const int n0 = bx << 5, k0 = by << 5;
#pragma unroll
    for (int i = 0; i < 4; ++i)
      tl[ty + i * 8][tx] = (_Float16)W[(long long)(k0 + ty + i * 8) * 1024 + n0 + tx];
    __syncthreads();
#pragma unroll
    for (int i = 0; i < 4; ++i)
      o[(long long)(n0 + ty + i * 8) * 1024 + k0 + tx] = tl[tx][ty + i * 8];
  }
}

// ---------------------------------------------------------------- QKV GEMM
// R11 kernel (736 TF, conflicts 0): 128x128 tile, BK=64, 4 waves 2x2.
__global__ __launch_bounds__(256)
void gemm_qkv(const _Float16* __restrict__ A, const _Float16* __restrict__ B,
              _Float16* __restrict__ Q, _Float16* __restrict__ Kh,
              _Float16* __restrict__ Vt) {
  const int bm = blockIdx.y, bn = blockIdx.x;
  const _Float16* Ab = A + (long long)bm * 128 * 1024;
  const _Float16* Bb = B + (long long)bn * 128 * 1024;

  __shared__ _Float16 As[128][64];
  __shared__ _Float16 Bs[128][64];

  const int tid = threadIdx.x;
  const int wave = tid >> 6, lane = tid & 63;
  const int quad = lane >> 4, lr = lane & 15;
  const int wm = (wave >> 1) << 6, wn = (wave & 1) << 6;
  const int srow = lane >> 3;
  const int goff = ((lane & 7) ^ srow) << 3;

  floatx4 acc[4][4] = {};
  const _Float16* ga = Ab + (long long)(wave * 8 + srow) * 1024 + goff;
  const _Float16* gb = Bb + (long long)(wave * 8 + srow) * 1024 + goff;

  for (int k0 = 0; k0 < 1024; k0 += 64) {
    __syncthreads();
#pragma unroll
    for (int c = 0; c < 4; ++c) {
      load16_lds(&As[wave * 8 + 32 * c][0], ga + c * 32 * 1024);
      load16_lds(&Bs[wave * 8 + 32 * c][0], gb + c * 32 * 1024);
    }
    ga += 64; gb += 64;
    __syncthreads();

#pragma unroll
    for (int kk = 0; kk < 2; ++kk) {
      half8 af[4], bf[4];
#pragma unroll
      for (int i = 0; i < 4; ++i) {
        const int ra = wm + (i << 4) + lr;
        const int rb = wn + (i << 4) + lr;
        af[i] = *(const half8*)&As[ra][(((kk << 2) + quad) ^ (ra & 7)) << 3];
        bf[i] = *(const half8*)&Bs[rb][(((kk << 2) + quad) ^ (rb & 7)) << 3];
      }
#pragma unroll
      for (int i = 0; i < 4; ++i)
#pragma unroll
        for (int j = 0; j < 4; ++j)
          acc[i][j] = __builtin_amdgcn_mfma_f32_16x16x32_f16(af[i], bf[j], acc[i][j], 0, 0, 0);
    }
  }

  const int colb = bn * 128 + wn + lr;
  const int rowb = bm * 128 + wm + (quad << 2);

  if (bn < 16) {
    _Float16* C = (bn < 8) ? Q : Kh;
    const int cb = colb & 1023;
#pragma unroll
    for (int i = 0; i < 4; ++i)
#pragma unroll
      for (int j = 0; j < 4; ++j)
#pragma unroll
        for (int r = 0; r < 4; ++r)
          C[(long long)(rowb + (i << 4) + r) * 1024 + cb + (j << 4)] =
              (_Float16)acc[i][j][r];
  } else {
    const int b = rowb >> 11;
    const int tb = rowb & 2047;
#pragma unroll
    for (int i = 0; i < 4; ++i) {
      const int tok = tb + (i << 4);
#pragma unroll
      for (int j = 0; j < 4; ++j) {
        const int d = (colb & 1023) + (j << 4);
        half4v v = { (_Float16)acc[i][j][0], (_Float16)acc[i][j][1],
                     (_Float16)acc[i][j][2], (_Float16)acc[i][j][3] };
        *(half4v*)&Vt[(long long)b * 2097152 + (long long)d * 2048 + tok] = v;
      }
    }
  }
}

// ---------------------------------------------------------------- S GEMM
// P[128 q x 128 k] = exp(mask(Q K^T/32) - m_tile) f16 in (0,1];
// per-tile row max M and row sum L, cross-wave combined via LDS.
// Triangular grid bn <= bm (136/batch) + XCD swizzle (8x17).
__global__ __launch_bounds__(256)
void gemm_s_exp(const _Float16* __restrict__ Q, const _Float16* __restrict__ Kh,
                _Float16* __restrict__ P, float* __restrict__ M,
                float* __restrict__ L) {
  // 136 = 8*17: 17 consecutive triangular ids per XCD -> same-bm blocks
  // (sharing the Q panel) co-reside in one XCD's L2.
  int t = (blockIdx.x & 7) * 17 + (blockIdx.x >> 3);
  int bm = 0;
  for (;;) { const int c = bm + 1; if (t < c) break; t -= c; ++bm; }
  const int bn = t;
  const int bz = blockIdx.y;

  const _Float16* Ab = Q  + (long long)bz * 2097152 + (long long)bm * 128 * 1024;
  const _Float16* Bb = Kh + (long long)bz * 2097152 + (long long)bn * 128 * 1024;

  __shared__ _Float16 As[128][64];
  __shared__ _Float16 Bs[128][64];
  __shared__ float sm_m[2][2][64];   // [wm-half][wn-half][local row]
  __shared__ float sm_s[2][2][64];

  const int tid = threadIdx.x;
  const int wave = tid >> 6, lane = tid & 63;
  const int quad = lane >> 4, lr = lane & 15;
  const int wm = (wave >> 1) << 6, wn = (wave & 1) << 6;
  const int wm1 = wave >> 1, wn1 = wave & 1;
  const int srow = lane >> 3;
  const int schunk = lane & 7;                 // LDS slot this lane fills
  const int goff = (schunk ^ srow) << 3;       // global chunk -> slot^(r&7)

  floatx4 acc[4][4] = {};
  const _Float16* ga = Ab + (long long)(wave * 8 + srow) * 1024 + goff;
  const _Float16* gb = Bb + (long long)(wave * 8 + srow) * 1024 + goff;

  half8 pa[4], pb[4];
#pragma unroll
  for (int c = 0; c < 4; ++c) {
    pa[c] = *(const half8*)(ga + c * 32 * 1024);
    pb[c] = *(const half8*)(gb + c * 32 * 1024);
  }

  for (int it = 0; it < 16; ++it) {
    __syncthreads();
#pragma unroll
    for (int c = 0; c < 4; ++c) {
      *(half8*)&As[wave * 8 + 32 * c + srow][schunk << 3] = pa[c];
      *(half8*)&Bs[wave * 8 + 32 * c + srow][schunk << 3] = pb[c];
    }
    __syncthreads();
    if (it + 1 < 16) {
      const int k1 = (it + 1) << 6;
#pragma unroll
      for (int c = 0; c < 4; ++c) {
        pa[c] = *(const half8*)(ga + c * 32 * 1024 + k1);
        pb[c] = *(const half8*)(gb + c * 32 * 1024 + k1);
      }
    }

#pragma unroll
    for (int kk = 0; kk < 2; ++kk) {
      half8 af[4], bf[4];
#pragma unroll
      for (int i = 0; i < 4; ++i) {
        const int ra = wm + (i << 4) + lr;
        const int rb = wn + (i << 4) + lr;
        af[i] = *(const half8*)&As[ra][(((kk << 2) + quad) ^ (ra & 7)) << 3];
        bf[i] = *(const half8*)&Bs[rb][(((kk << 2) + quad) ^ (rb & 7)) << 3];
      }
#pragma unroll
      for (int i = 0; i < 4; ++i)
#pragma unroll
        for (int j = 0; j < 4; ++j)
          acc[i][j] = __builtin_amdgcn_mfma_f32_16x16x32_f16(af[i], bf[j], acc[i][j], 0, 0, 0);
    }
  }

  // ---- epilogue: per-wave masked max -> cross-wn combine -> exp -> sums ->
  // single-writer M/L (wn1==0 wave).
  const int colb = bn * 128 + wn + lr;
  const int rowb = bm * 128 + wm + (quad << 2);
  _Float16* Pb = P + (long long)bz * 4194304;
  const float scl = 0.03125f;

  float mx[4][4], rs[4][4];
#pragma unroll
  for (int i = 0; i < 4; ++i)
#pragma unroll
    for (int r = 0; r < 4; ++r) { mx[i][r] = -3.0e38f; rs[i][r] = 0.f; }

#pragma unroll
  for (int i = 0; i < 4; ++i)
#pragma unroll
    for (int j = 0; j < 4; ++j)
#pragma unroll
      for (int r = 0; r < 4; ++r) {
        const int qr = rowb + (i << 4) + r;
        const int kcol = colb + (j << 4);
        if (kcol <= qr) mx[i][r] = fmaxf(mx[i][r], acc[i][j][r] * scl);
      }
#pragma unroll
  for (int i = 0; i < 4; ++i)
#pragma unroll
    for (int r = 0; r < 4; ++r) {
#pragma unroll
      for (int off = 1; off < 16; off <<= 1)
        mx[i][r] = fmaxf(mx[i][r], __shfl_xor(mx[i][r], off));
    }

  if (lr == 0) {
#pragma unroll
    for (int i = 0; i < 4; ++i)
#pragma unroll
      for (int r = 0; r < 4; ++r)
        sm_m[wm1][wn1][(i << 4) + (quad << 2) + r] = mx[i][r];
  }
  __syncthreads();
  float mt[4][4];
#pragma unroll
  for (int i = 0; i < 4; ++i)
#pragma unroll
    for (int r = 0; r < 4; ++r)
      mt[i][r] = fmaxf(mx[i][r], sm_m[wm1][wn1 ^ 1][(i << 4) + (quad << 2) + r]);

#pragma unroll
  for (int i = 0; i < 4; ++i)
#pragma unroll
    for (int j = 0; j < 4; ++j)
#pragma unroll
      for (int r = 0; r < 4; ++r) {
        const int qr = rowb + (i << 4) + r;
        const int kcol = colb + (j << 4);
        const float pv =
            (kcol <= qr) ? __expf(acc[i][j][r] * scl - mt[i][r]) : 0.f;
        Pb[(long long)qr * 2048 + kcol] = (_Float16)pv;
        rs[i][r] += pv;
      }

#pragma unroll
  for (int i = 0; i < 4; ++i)
#pragma unroll
    for (int r = 0; r < 4; ++r) {
#pragma unroll
      for (int off = 1; off < 16; off <<= 1)
        rs[i][r] += __shfl_xor(rs[i][r], off);
    }

  if (lr == 0) {
#pragma unroll
    for (int i = 0; i < 4; ++i)
#pragma unroll
      for (int r = 0; r < 4; ++r)
        sm_s[wm1][wn1][(i << 4) + (quad << 2) + r] = rs[i][r];
  }
  __syncthreads();
  if (wn1 == 0 && lr == 0) {
    float* Mb = M + ((long long)bz * 16 + bn) * 2048;
    float* Lb = L + ((long long)bz * 16 + bn) * 2048;
#pragma unroll
    for (int i = 0; i < 4; ++i)
#pragma unroll
      for (int r = 0; r < 4; ++r) {
        const int lrow = (i << 4) + (quad << 2) + r;
        const int row = rowb + (i << 4) + r;
        Mb[row] = mt[i][r];
        Lb[row] = rs[i][r] + sm_s[wm1][1][lrow];
      }
  }
}

// ---------------------------------------------------------------- PV GEMM
// Swapped: C[128 d x 128 q] = Vt_panel . P_panel^T; out[q][d] = C^T * 1/l.
// A = Vt (rows d, ld 2048), B = P (rows q, ld 2048, F-scaled at staging).
// Prologue folds combine: per-row m_g/F/1/l from M/L into LDS (no F/lg bufs).
// XCD map: 4 bm-groups ({15,14,1,0}...{9,8,7,6}, each sum(bm+1)=34, heavy
// pair first) x 2 dn-halves; Keff = 128*(bm+1).
__global__ __launch_bounds__(256)
void gemm_pv(const _Float16* __restrict__ P, const _Float16* __restrict__ Vt,
             const float* __restrict__ M, const float* __restrict__ L,
             float* __restrict__ out) {
  const int lid = blockIdx.x + (blockIdx.y << 3) + (blockIdx.z << 7);
  const int xcd = lid & 7;
  const int s = lid >> 3;              // 0..63
  const int p = s >> 4;                // 0..3 (heavy-first within group)
  const int dnl = (s >> 2) & 3;
  const int bz = s & 3;
  const int bmg = xcd >> 1, dng = xcd & 1;
  const int bm = (p < 2) ? (15 - 2 * bmg - p) : (2 * bmg + (3 - p));
  const int dn = dng * 4 + dnl;
  const int niter = 2 * (bm + 1);      // Keff/64

  const _Float16* Ab = Vt + (long long)bz * 2097152 + (long long)dn * 128 * 2048;
  const _Float16* Bb = P  + (long long)bz * 4194304 + (long long)bm * 128 * 2048;

  __shared__ _Float16 As[128][64];
  __shared__ _Float16 Bs[128][64];
  __shared__ float F_lds[16][128];
  __shared__ float linv_lds[128];

  const int tid = threadIdx.x;
  const int wave = tid >> 6, lane = tid & 63;
  const int quad = lane >> 4, lr = lane & 15;
  const int wm = (wave >> 1) << 6, wn = (wave & 1) << 6;
  const int srow = lane >> 3;
  const int schunk = lane & 7;
  const int goff = (schunk ^ srow) << 3;
  const int lrow0 = wave * 8 + srow;   // tile-local staged row, chunk c: +32c

  // ---- folded combine: rows q_local = tid (<128) of this bm-panel ----
  if (tid < 128) {
    const float* Mb = M + (long long)bz * 32768 + bm * 128 + tid;
    const float* Lb = L + (long long)bz * 32768 + bm * 128 + tid;
    float mg = -3.0e38f;
    for (int t = 0; t <= bm; ++t) mg = fmaxf(mg, Mb[t * 2048]);
    float ssum = 0.f;
    for (int t = 0; t <= bm; ++t) {
      const float f = __expf(Mb[t * 2048] - mg);
      F_lds[t][tid] = f;
      ssum += f * Lb[t * 2048];
    }
    linv_lds[tid] = 1.0f / ssum;
  }

  floatx4 acc[4][4] = {};
  const _Float16* ga = Ab + (long long)lrow0 * 2048 + goff;
  const _Float16* gb = Bb + (long long)lrow0 * 2048 + goff;

  half8 pa[4], pb[4];
#pragma unroll
  for (int c = 0; c < 4; ++c) {
    pa[c] = *(const half8*)(ga + (long long)c * 32 * 2048);
    pb[c] = *(const half8*)(gb + (long long)c * 32 * 2048);
  }

  for (int it = 0; it < niter; ++it) {
    __syncthreads();
    const int kt = it >> 1;
#pragma unroll
    for (int c = 0; c < 4; ++c) {
      *(half8*)&As[wave * 8 + 32 * c + srow][schunk << 3] = pa[c];
      *(half8*)&Bs[wave * 8 + 32 * c + srow][schunk << 3] =
          pb[c] * (_Float16)F_lds[kt][lrow0 + 32 * c];
    }
    __syncthreads();
    if (it + 1 < niter) {
      const int k1 = (it + 1) << 6;
#pragma unroll
      for (int c = 0; c < 4; ++c) {
        pa[c] = *(const half8*)(ga + (long long)c * 32 * 2048 + k1);
        pb[c] = *(const half8*)(gb + (long long)c * 32 * 2048 + k1);
      }
    }

#pragma unroll
    for (int kk = 0; kk < 2; ++kk) {
      half8 af[4], bf[4];
#pragma unroll
      for (int i = 0; i < 4; ++i) {
        const int ra = wm + (i << 4) + lr;
        const int rb = wn + (i << 4) + lr;
        af[i] = *(const half8*)&As[ra][(((kk << 2) + quad) ^ (ra & 7)) << 3];
        bf[i] = *(const half8*)&Bs[rb][(((kk << 2) + quad) ^ (rb & 7)) << 3];
      }
#pragma unroll
      for (int i = 0; i < 4; ++i)
#pragma unroll
        for (int j = 0; j < 4; ++j)
          acc[i][j] = __builtin_amdgcn_mfma_f32_16x16x32_f16(af[i], bf[j], acc[i][j], 0, 0, 0);
    }
  }

  // epilogue: C[d_local][q_local]; d_local = wm+16i+(quad<<2)+r (4 consec
  // regs = 4 consec d -> float4), q_local = wn+16j+lr.
  float* Cb = out + (long long)bz * 2097152;
  const int d0 = dn * 128 + wm + (quad << 2);
  const int q0 = bm * 128 + wn + lr;

  float linv[4];
#pragma unroll
  for (int j = 0; j < 4; ++j) linv[j] = linv_lds[wn + (j << 4) + lr];

#pragma unroll
  for (int i = 0; i < 4; ++i)
#pragma unroll
    for (int j = 0; j < 4; ++j) {
      float4 v = { acc[i][j][0] * linv[j], acc[i][j][1] * linv[j],
                   acc[i][j][2] * linv[j], acc[i][j][3] * linv[j] };
      *(float4*)&Cb[(long long)(q0 + (j << 4)) * 1024 + d0 + (i << 4)] = v;
    }
}

// ---------------------------------------------------------------- launch

extern "C" void kernel_launch(void* const* d_in, const int* in_sizes, int n_in,
                              void* d_out, int out_size, void* d_ws, size_t ws_size,
                              hipStream_t stream) {
  const float* x  = (const float*)d_in[0];
  const float* Wq = (const float*)d_in[1];
  const float* Wk = (const float*)d_in[2];
  const float* Wv = (const float*)d_in[3];
  float* out = (float*)d_out;

  char* ws = (char*)d_ws;
  _Float16* xh = (_Float16*)(ws);               // 8192x1024 f16   (16 MiB)
  _Float16* Wt = (_Float16*)(ws + 16777216);    // 3072x1024 f16   ( 6 MiB)
  _Float16* Q  = (_Float16*)(ws + 23068672);    // 8192x1024 f16
  _Float16* Kh = (_Float16*)(ws + 39845888);    // 8192x1024 f16
  _Float16* Vt = (_Float16*)(ws + 56623104);    // 4x1024x2048 f16
  _Float16* P  = (_Float16*)(ws + 73400320);    // 4x2048x2048 f16 (exp-m_tile)
  float*    M  = (float*)   (ws + 106954752);   // [4][16][2048] tile row max
  float*    L  = (float*)   (ws + 107479040);   // [4][16][2048] tile row sum

  // merged: x convert + W transpose
  prep<<<11264, 256, 0, stream>>>(x, xh, Wq, Wk, Wv, Wt);

  // fused QKV: [8192,1024] x [3072,1024]^T
  gemm_qkv<<<dim3(24, 64), 256, 0, stream>>>(xh, Wt, Q, Kh, Vt);

  // P = exp(mask(Q K^T / 32) - m_tile), per-tile m/l; triangular grid
  gemm_s_exp<<<dim3(136, 4), 256, 0, stream>>>(Q, Kh, P, M, L);

  // out = (sum F*P V) / l_g; swapped operands, combine folded in
  gemm_pv<<<dim3(8, 16, 4), 256, 0, stream>>>(P, Vt, M, L, out);
}